// Round 8
// baseline (190.794 us; speedup 1.0000x reference)
//
#include <hip/hip_runtime.h>
#include <stdint.h>
#include <math.h>

#define E_DIM 1024
#define W_DIM 1024
#define EW 1048576L   // 1024*1024

typedef _Float16 h16;
typedef __attribute__((ext_vector_type(8))) _Float16 h8;
typedef __attribute__((ext_vector_type(4))) float f4;

__device__ __forceinline__ void async_copy16(h16* lds, const h16* g) {
    __builtin_amdgcn_global_load_lds(
        (const __attribute__((address_space(1))) void*)g,
        (__attribute__((address_space(3))) void*)lds, 16, 0, 0);
}

// ---------------------------------------------------------------------------
// prep: z<12 -> transpose-convert x [12][E][W] fp32 -> [12][W][E] fp16;
//       z>=12 -> convert weight (z-12) fp32 -> fp16 into wh[LK|LQ|LV|M].
// ---------------------------------------------------------------------------
__global__ __launch_bounds__(256) void prep(
    const float* __restrict__ x, const float* __restrict__ LK,
    const float* __restrict__ LQ, const float* __restrict__ LV,
    const float* __restrict__ Mw, h16* __restrict__ xt, h16* __restrict__ wh)
{
    __shared__ float Ts[64][65];
    const int z = blockIdx.z;
    const int t = threadIdx.x;
    if (z < 12) {
        const float* src = x + (long)z * EW;   // [e][w]
        h16* dst = xt + (long)z * EW;          // [w][e]
        const int e0 = blockIdx.y * 64, w0 = blockIdx.x * 64;
        const int r = t >> 4, c4 = (t & 15) * 4;
        #pragma unroll
        for (int p = 0; p < 4; ++p) {
            float4 v = *reinterpret_cast<const float4*>(src + (long)(e0 + r + p * 16) * W_DIM + w0 + c4);
            Ts[c4 + 0][r + p * 16] = v.x;
            Ts[c4 + 1][r + p * 16] = v.y;
            Ts[c4 + 2][r + p * 16] = v.z;
            Ts[c4 + 3][r + p * 16] = v.w;
        }
        __syncthreads();
        #pragma unroll
        for (int p = 0; p < 4; ++p) {
            int wr = r + p * 16;
            union { h16 h[4]; uint2 u; } o;
            o.h[0] = (h16)Ts[wr][c4 + 0];
            o.h[1] = (h16)Ts[wr][c4 + 1];
            o.h[2] = (h16)Ts[wr][c4 + 2];
            o.h[3] = (h16)Ts[wr][c4 + 3];
            *reinterpret_cast<uint2*>(dst + (long)(w0 + wr) * E_DIM + e0 + c4) = o.u;
        }
    } else {
        const float* srcs[4] = {LK, LQ, LV, Mw};
        const float* s = srcs[z - 12];
        h16* o = wh + (long)(z - 12) * EW;
        long base = ((long)(blockIdx.y * 16 + blockIdx.x)) * 1024 + t;  // float4 idx
        #pragma unroll
        for (int k = 0; k < 4; ++k) {
            long i = base + k * 256;
            float4 v = reinterpret_cast<const float4*>(s)[i];
            union { h16 h[4]; uint2 u; } u;
            u.h[0] = (h16)v.x; u.h[1] = (h16)v.y; u.h[2] = (h16)v.z; u.h[3] = (h16)v.w;
            reinterpret_cast<uint2*>(o)[i] = u.u;
        }
    }
}

// ---------------------------------------------------------------------------
// Fused projection GEMMs (K, Q, V) — 256x256 tile, BK=64, 8 waves (2Mx4N),
// 2-K-tile double-buffer (128 KB LDS), COUNTED-vmcnt pipeline:
//   stage(T+1) -> s_waitcnt vmcnt(8) (tile T landed, T+1 stays in flight
//   across the barrier) -> raw s_barrier -> 64 MFMA/wave (B-frag reuse)
//   -> raw s_barrier.  NO __syncthreads in the K-loop (its vmcnt(0) drain
//   is the m97-structure's ~20% stall).  Granule XOR swizzle (0 conflicts).
// ---------------------------------------------------------------------------
__global__ __launch_bounds__(512) void gemm_proj3(
    const h16* __restrict__ xh, const h16* __restrict__ Wts,
    h16* __restrict__ KQV)
{
    __shared__ h16 As[2][256 * 64];   // 32 KB per buf
    __shared__ h16 Bs[2][256 * 64];   // total 128 KB

    const int t = threadIdx.x;              // 0..511
    const int wave = t >> 6, lane = t & 63;
    const int quad = lane >> 4, l16 = lane & 15;
    const int mi = wave >> 2, ni = wave & 3;
    const int wm = mi * 128, wn = ni * 64;

    // XCD swizzle: 192 wgs, 192%8==0 -> bijective chunk remap (chunk 24)
    const int lin = (int)blockIdx.x + ((int)blockIdx.y << 2) + ((int)blockIdx.z << 4);
    const int swz = (lin & 7) * 24 + (lin >> 3);
    const int bx = swz & 3, by = (swz >> 2) & 3, zz = swz >> 4;

    const int m0 = by * 256, n0 = bx * 256;

    const int proj = zz >> 2, bz = zz & 3;
    const h16 *A, *Bt; h16* C;
    if (proj == 0)      { A = xh + bz * EW;       Bt = Wts;          C = KQV + bz * EW; }
    else if (proj == 1) { A = xh + (4 + bz) * EW; Bt = Wts + EW;     C = KQV + (4 + bz) * EW; }
    else                { A = Wts + 2 * EW;       Bt = xh + (8 + bz) * EW; C = KQV + (8 + bz) * EW; }

    f4 acc[8][4] = {};

    // stage one K-tile (256 rows x 64 k, A+B) into buf: 8 gload_lds/thread
    auto stage = [&](int buf, int k0) {
        #pragma unroll
        for (int j = 0; j < 4; ++j) {
            int g = j * 512 + t, row = g >> 3, cg = (g & 7) ^ (row & 7);
            async_copy16(&As[buf][g * 8], A  + (long)(m0 + row) * E_DIM + k0 + cg * 8);
            async_copy16(&Bs[buf][g * 8], Bt + (long)(n0 + row) * E_DIM + k0 + cg * 8);
        }
    };

    stage(0, 0);   // prologue: tile 0 in flight

    for (int T = 0; T < 16; ++T) {
        if (T + 1 < 16) {
            stage((T + 1) & 1, (T + 1) * 64);                 // keep 8 in flight
            asm volatile("s_waitcnt vmcnt(8)" ::: "memory");  // tile T landed
        } else {
            asm volatile("s_waitcnt vmcnt(0)" ::: "memory");
        }
        __builtin_amdgcn_s_barrier();   // raw: T+1's loads stay in flight

        const h16* as = As[T & 1];
        const h16* bs = Bs[T & 1];

        #pragma unroll
        for (int c = 0; c < 2; ++c) {
            h8 bv[4];
            #pragma unroll
            for (int j = 0; j < 4; ++j) {
                int rb = wn + j * 16 + l16;
                bv[j] = *reinterpret_cast<const h8*>(&bs[(rb * 8 + ((c * 4 + quad) ^ (l16 & 7))) * 8]);
            }
            #pragma unroll
            for (int fh = 0; fh < 2; ++fh) {
                h8 av[4];
                #pragma unroll
                for (int i = 0; i < 4; ++i) {
                    int ra = wm + fh * 64 + i * 16 + l16;
                    av[i] = *reinterpret_cast<const h8*>(&as[(ra * 8 + ((c * 4 + quad) ^ (l16 & 7))) * 8]);
                }
                __builtin_amdgcn_s_setprio(1);
                #pragma unroll
                for (int i = 0; i < 4; ++i)
                    #pragma unroll
                    for (int j = 0; j < 4; ++j)
                        acc[fh * 4 + i][j] = __builtin_amdgcn_mfma_f32_16x16x32_f16(av[i], bv[j], acc[fh * 4 + i][j], 0, 0, 0);
                __builtin_amdgcn_s_setprio(0);
            }
        }
        __builtin_amdgcn_s_barrier();   // readers done before next stage lands
    }

    #pragma unroll
    for (int mt = 0; mt < 8; ++mt)
        #pragma unroll
        for (int i = 0; i < 4; ++i) {
            int m = m0 + wm + mt * 16 + quad * 4 + i;
            #pragma unroll
            for (int nt = 0; nt < 4; ++nt)
                C[(long)m * W_DIM + n0 + wn + nt * 16 + l16] = (h16)acc[mt][nt][i];
        }
}

// ---------------------------------------------------------------------------
// Output GEMM, batch-fused: out = M[1024x1024] x Ao[4096x1024]^T (+bias).
// 64x128 tiles -> 512 blocks (R1-proven structure).
// ---------------------------------------------------------------------------
__global__ __launch_bounds__(256) void gemm_out(
    const h16* __restrict__ A, const h16* __restrict__ Bt,
    float* __restrict__ C, const float* __restrict__ bias)
{
    __shared__ h16 As[64 * 64];
    __shared__ h16 Bs[128 * 64];

    const int t = threadIdx.x;
    const int wave = t >> 6, lane = t & 63;
    const int quad = lane >> 4, l16 = lane & 15;
    const int m0 = blockIdx.y * 64, n0 = blockIdx.x * 128;
    const int wm = (wave >> 1) * 32, wn = (wave & 1) * 64;

    f4 acc[2][4] = {};

    for (int k0 = 0; k0 < 1024; k0 += 64) {
        __syncthreads();
        #pragma unroll
        for (int j = 0; j < 2; ++j) {
            int g = j * 256 + t, row = g >> 3, cg = (g & 7) ^ (row & 7);
            async_copy16(&As[g * 8], A + (long)(m0 + row) * E_DIM + k0 + cg * 8);
        }
        #pragma unroll
        for (int j = 0; j < 4; ++j) {
            int g = j * 256 + t, row = g >> 3, cg = (g & 7) ^ (row & 7);
            async_copy16(&Bs[g * 8], Bt + (long)(n0 + row) * E_DIM + k0 + cg * 8);
        }
        __syncthreads();

        h8 av[2][2], bv[4][2];
        #pragma unroll
        for (int c = 0; c < 2; ++c) {
            #pragma unroll
            for (int mt = 0; mt < 2; ++mt) {
                int r = wm + mt * 16 + l16;
                av[mt][c] = *reinterpret_cast<const h8*>(&As[(r * 8 + ((c * 4 + quad) ^ (l16 & 7))) * 8]);
            }
            #pragma unroll
            for (int nt = 0; nt < 4; ++nt) {
                int r = wn + nt * 16 + l16;
                bv[nt][c] = *reinterpret_cast<const h8*>(&Bs[(r * 8 + ((c * 4 + quad) ^ (l16 & 7))) * 8]);
            }
        }
        #pragma unroll
        for (int c = 0; c < 2; ++c)
            #pragma unroll
            for (int mt = 0; mt < 2; ++mt)
                #pragma unroll
                for (int nt = 0; nt < 4; ++nt)
                    acc[mt][nt] = __builtin_amdgcn_mfma_f32_16x16x32_f16(av[mt][c], bv[nt][c], acc[mt][nt], 0, 0, 0);
    }

    #pragma unroll
    for (int mt = 0; mt < 2; ++mt)
        #pragma unroll
        for (int i = 0; i < 4; ++i) {
            int m = m0 + wm + mt * 16 + quad * 4 + i;
            float bv_ = bias ? bias[m] : 0.f;
            #pragma unroll
            for (int nt = 0; nt < 4; ++nt) {
                int n = n0 + wn + nt * 16 + l16;   // n = b*1024 + w
                C[(long)(n >> 10) * EW + (long)m * W_DIM + (n & 1023)] = acc[mt][nt][i] + bv_;
            }
        }
}

// ---------------------------------------------------------------------------
// MFMA flash attention (softmax over q), 8-WAVE blocks (512 thr) — R6 version.
// ---------------------------------------------------------------------------
__global__ __launch_bounds__(512) void attn_mfma(
    const h16* __restrict__ Kt, const h16* __restrict__ Qt,
    const h16* __restrict__ V, h16* __restrict__ AoT)
{
    __shared__ h16 Qs[2][64 * 64];   // [q][d] swizzled granules (8 KB each)
    __shared__ h16 Vs[2][64 * 64];   // [d][q] swizzled granules
    __shared__ h16 Ps[8][16 * 64];   // per-wave P^T [k16][q64] swizzled granules

    const int t = threadIdx.x, wave = t >> 6, lane = t & 63;
    const int quad = lane >> 4, l16 = lane & 15;
    const int y = blockIdx.y;
    const int b = y >> 4, h = y & 15;
    const int cxor = (y & 7) ^ (((y >> 5) & 1) ? 7 : 0);
    const int ktb = (int)blockIdx.x ^ cxor;     // 0..7; id & id+256 complementary
    const int nit = 2 * ktb + 2;                // staging iterations (block-wide)
    const int kwave = ktb * 128 + wave * 16;    // wave's first k column
    const int kc = kwave + l16;                 // this lane's k column

    const h16* Ktb_ = Kt + (long)b * EW + h * 64;
    const h16* Qtb  = Qt + (long)b * EW + h * 64;
    const h16* Vb   = V  + (long)b * EW + (long)(h * 64) * W_DIM;
    h16* Pw = &Ps[wave][0];

    // K in registers: half c -> K^T[kc][c*32 + quad*8 + j]
    h8 kb0 = *reinterpret_cast<const h8*>(Ktb_ + (long)kc * E_DIM + quad * 8);
    h8 kb1 = *reinterpret_cast<const h8*>(Ktb_ + (long)kc * E_DIM + 32 + quad * 8);

    // stage tile 0 into buf 0 (512 threads x 16B = full 8 KB tile each)
    {
        int row = t >> 3, cg = (t & 7) ^ (row & 7);
        async_copy16(&Qs[0][t * 8], Qtb + (long)row * E_DIM + cg * 8);
        async_copy16(&Vs[0][t * 8], Vb + (long)row * W_DIM + cg * 8);
    }

    const float L2E = 1.442695041f;
    float mr = -1e30f, ls = 0.f;
    f4 O[4] = {};

    for (int it = 0; it < nit; ++it) {
        const int q0 = it * 64;
        __syncthreads();   // drains DMA for buf it&1; prev iter's readers done
        if (it + 1 < nit) {
            const int nb = (it + 1) & 1, q1 = q0 + 64;
            int row = t >> 3, cg = (t & 7) ^ (row & 7);
            async_copy16(&Qs[nb][t * 8], Qtb + (long)(q1 + row) * E_DIM + cg * 8);
            async_copy16(&Vs[nb][t * 8], Vb + (long)row * W_DIM + q1 + cg * 8);
        }
        if (q0 > kwave + 15) continue;   // wave fully masked on this q-tile

        const h16* qs = Qs[it & 1];
        const h16* vs = Vs[it & 1];

        // S^T[q][k]: row q = q0+nt*16+quad*4+i, col k = kc
        f4 S[4];
        __builtin_amdgcn_s_setprio(1);
        #pragma unroll
        for (int nt = 0; nt < 4; ++nt) {
            int row = nt * 16 + l16;
            h8 a0 = *reinterpret_cast<const h8*>(&qs[(row * 8 + (quad ^ (l16 & 7))) * 8]);
            h8 a1 = *reinterpret_cast<const h8*>(&qs[(row * 8 + ((4 + quad) ^ (l16 & 7))) * 8]);
            f4 s = {};
            s = __builtin_amdgcn_mfma_f32_16x16x32_f16(a0, kb0, s, 0, 0, 0);
            s = __builtin_amdgcn_mfma_f32_16x16x32_f16(a1, kb1, s, 0, 0, 0);
            S[nt] = s;
        }
        __builtin_amdgcn_s_setprio(0);

        if (it >= 2 * ktb) {   // diagonal region: mask q > k
            #pragma unroll
            for (int nt = 0; nt < 4; ++nt)
                #pragma unroll
                for (int i = 0; i < 4; ++i)
                    if (q0 + nt * 16 + quad * 4 + i > kc) S[nt][i] = -1e30f;
        }

        // tile max per column (in-lane tree + cross-quad xor16/xor32)
        float mx = -1e30f;
        #pragma unroll
        for (int nt = 0; nt < 4; ++nt) {
            float t0 = fmaxf(fmaxf(S[nt][0], S[nt][1]), fmaxf(S[nt][2], S[nt][3]));
            mx = fmaxf(mx, t0);
        }
        mx = fmaxf(mx, __shfl_xor(mx, 16));
        mx = fmaxf(mx, __shfl_xor(mx, 32));

        // defer-max: only rescale when the column max grew past THR=8
        if (__any(mx - mr > 8.f)) {
            float nm = fmaxf(mr, mx);
            float al = exp2f((mr - nm) * L2E);
            mr = nm;
            ls *= al;
            #pragma unroll
            for (int dt = 0; dt < 4; ++dt)
                #pragma unroll
                for (int i = 0; i < 4; ++i) O[dt][i] *= al;
        }

        const float mc = mr * L2E;
        float tsa = 0.f, tsb = 0.f;
        #pragma unroll
        for (int nt = 0; nt < 4; ++nt)
            #pragma unroll
            for (int i = 0; i < 4; ++i) {
                float p = exp2f(fmaf(S[nt][i], L2E, -mc));
                S[nt][i] = p;
                if (i & 1) tsb += p; else tsa += p;
            }
        float ts = tsa + tsb;
        ts += __shfl_xor(ts, 16);
        ts += __shfl_xor(ts, 32);
        ls += ts;

        // P^T -> per-wave LDS: row l16, swizzled granules
        #pragma unroll
        for (int nt = 0; nt < 4; ++nt) {
            int sg = ((nt * 2 + (quad >> 1)) ^ (l16 & 7)) * 8 + (quad & 1) * 4;
            union { h16 hh[4]; uint2 u2; } u0;
            #pragma unroll
            for (int i = 0; i < 4; ++i) u0.hh[i] = (h16)S[nt][i];
            *reinterpret_cast<uint2*>(Pw + l16 * 64 + sg) = u0.u2;
        }
        asm volatile("" ::: "memory");   // DS in-order per wave; read after write

        // OUT^T[d][k] += V[d][q] * P[q][k]
        __builtin_amdgcn_s_setprio(1);
        #pragma unroll
        for (int c = 0; c < 2; ++c) {
            int sg = ((c * 4 + quad) ^ (l16 & 7)) * 8;
            h8 pb = *reinterpret_cast<const h8*>(Pw + l16 * 64 + sg);
            #pragma unroll
            for (int dt = 0; dt < 4; ++dt) {
                int r = dt * 16 + l16;
                h8 va = *reinterpret_cast<const h8*>(&vs[(r * 8 + ((c * 4 + quad) ^ (l16 & 7))) * 8]);
                O[dt] = __builtin_amdgcn_mfma_f32_16x16x32_f16(va, pb, O[dt], 0, 0, 0);
            }
        }
        __builtin_amdgcn_s_setprio(0);
    }

    // epilogue: O cols k=l16, rows d -> transpose via Pw, store rows of AoT
    const float inv = 0.03125f / ls;
    #pragma unroll
    for (int dt = 0; dt < 4; ++dt) {
        int sg = ((dt * 2 + (quad >> 1)) ^ (l16 & 7)) * 8 + (quad & 1) * 4;
        union { h16 hh[4]; uint2 u2; } u0;
        #pragma unroll
        for (int i = 0; i < 4; ++i) u0.hh[i] = (h16)(O[dt][i] * inv);
        *reinterpret_cast<uint2*>(Pw + l16 * 64 + sg) = u0.u2;
    }
    asm volatile("" ::: "memory");
    #pragma unroll
    for (int j = 0; j < 2; ++j) {
        int sg = ((quad * 2 + j) ^ (l16 & 7)) * 8;
        uint4 vv = *reinterpret_cast<const uint4*>(Pw + l16 * 64 + sg);
        *reinterpret_cast<uint4*>(AoT + (long)b * EW + (long)(kwave + l16) * E_DIM
                                  + h * 64 + quad * 16 + j * 8) = vv;
    }
}

// ---------------------------------------------------------------------------
extern "C" void kernel_launch(void* const* d_in, const int* in_sizes, int n_in,
                              void* d_out, int out_size, void* d_ws, size_t ws_size,
                              hipStream_t stream)
{
    const float* x  = (const float*)d_in[0];  // [3][B][E][W]; x[0]->K, x[1]->Q, x[2]->V
    const float* LQ = (const float*)d_in[1];
    const float* LK = (const float*)d_in[2];
    const float* LV = (const float*)d_in[3];
    const float* Mw = (const float*)d_in[4];
    const float* bb = (const float*)d_in[5];
    float* out = (float*)d_out;
    h16* ws = (h16*)d_ws;

    h16* xh  = ws;                    // [12][W][E] transposed x
    h16* LKh = ws + 12 * EW;          // weights [LK|LQ|LV|M]
    h16* Mh  = ws + 15 * EW;
    h16* Kp  = ws + 16 * EW;          // [B][W][E] (K^T)
    h16* Qp  = ws + 20 * EW;          // [B][W][E] (Q^T)
    h16* Vp  = ws + 24 * EW;          // [B][E][W] (V)
    h16* Ao  = ws + 28 * EW;          // [B][W][E] (attn out^T) = [4096][1024]

    dim3 blk(256);
    prep<<<dim3(16, 16, 16), blk, 0, stream>>>(x, LK, LQ, LV, Mw, xh, LKh);
    gemm_proj3<<<dim3(4, 4, 12), dim3(512), 0, stream>>>(xh, LKh, Kp);
    attn_mfma<<<dim3(8, 64), dim3(512), 0, stream>>>(Kp, Qp, Vp, Ao);
    gemm_out<<<dim3(32, 16), blk, 0, stream>>>(Mh, Ao, out, bb);
}

// Round 9
// 188.660 us; speedup vs baseline: 1.0113x; 1.0113x over previous
//
#include <hip/hip_runtime.h>
#include <stdint.h>
#include <math.h>

#define E_DIM 1024
#define W_DIM 1024
#define EW 1048576L   // 1024*1024

typedef _Float16 h16;
typedef __attribute__((ext_vector_type(8))) _Float16 h8;
typedef __attribute__((ext_vector_type(4))) float f4;

__device__ __forceinline__ void async_copy16(h16* lds, const h16* g) {
    __builtin_amdgcn_global_load_lds(
        (const __attribute__((address_space(1))) void*)g,
        (__attribute__((address_space(3))) void*)lds, 16, 0, 0);
}

// ---------------------------------------------------------------------------
// prep: z<12 -> transpose-convert x [12][E][W] fp32 -> [12][W][E] fp16;
//       z>=12 -> convert weight (z-12) fp32 -> fp16 into wh[LK|LQ|LV|M].
// ---------------------------------------------------------------------------
__global__ __launch_bounds__(256) void prep(
    const float* __restrict__ x, const float* __restrict__ LK,
    const float* __restrict__ LQ, const float* __restrict__ LV,
    const float* __restrict__ Mw, h16* __restrict__ xt, h16* __restrict__ wh)
{
    __shared__ float Ts[64][65];
    const int z = blockIdx.z;
    const int t = threadIdx.x;
    if (z < 12) {
        const float* src = x + (long)z * EW;   // [e][w]
        h16* dst = xt + (long)z * EW;          // [w][e]
        const int e0 = blockIdx.y * 64, w0 = blockIdx.x * 64;
        const int r = t >> 4, c4 = (t & 15) * 4;
        #pragma unroll
        for (int p = 0; p < 4; ++p) {
            float4 v = *reinterpret_cast<const float4*>(src + (long)(e0 + r + p * 16) * W_DIM + w0 + c4);
            Ts[c4 + 0][r + p * 16] = v.x;
            Ts[c4 + 1][r + p * 16] = v.y;
            Ts[c4 + 2][r + p * 16] = v.z;
            Ts[c4 + 3][r + p * 16] = v.w;
        }
        __syncthreads();
        #pragma unroll
        for (int p = 0; p < 4; ++p) {
            int wr = r + p * 16;
            union { h16 h[4]; uint2 u; } o;
            o.h[0] = (h16)Ts[wr][c4 + 0];
            o.h[1] = (h16)Ts[wr][c4 + 1];
            o.h[2] = (h16)Ts[wr][c4 + 2];
            o.h[3] = (h16)Ts[wr][c4 + 3];
            *reinterpret_cast<uint2*>(dst + (long)(w0 + wr) * E_DIM + e0 + c4) = o.u;
        }
    } else {
        const float* srcs[4] = {LK, LQ, LV, Mw};
        const float* s = srcs[z - 12];
        h16* o = wh + (long)(z - 12) * EW;
        long base = ((long)(blockIdx.y * 16 + blockIdx.x)) * 1024 + t;  // float4 idx
        #pragma unroll
        for (int k = 0; k < 4; ++k) {
            long i = base + k * 256;
            float4 v = reinterpret_cast<const float4*>(s)[i];
            union { h16 h[4]; uint2 u; } u;
            u.h[0] = (h16)v.x; u.h[1] = (h16)v.y; u.h[2] = (h16)v.z; u.h[3] = (h16)v.w;
            reinterpret_cast<uint2*>(o)[i] = u.u;
        }
    }
}

// ---------------------------------------------------------------------------
// Fused projection GEMMs (K, Q, V) — 256x256 tile, FINE-PHASE pipeline:
//  - K split into 32 sub-tiles of BK=32; 4 LDS buffers (4 x 32 KB = 128 KB)
//    -> prefetch depth 3 sub-tiles (~96 K-cols ~ HBM latency class)
//  - 2 phases per sub-tile, each {ds_read frags || stage 2 gload_lds ->
//    s_barrier -> setprio 16 MFMA setprio -> s_barrier} (m201 cadence)
//  - counted vmcnt(8) once per sub-tile boundary: certifies tile H+1 while
//    H+2/H+3 stay in flight across barriers; taper 8->4->0 at epilogue only
//  - granule XOR swizzle (<=2-way bank aliasing, free per m136)
// ---------------------------------------------------------------------------
__global__ __launch_bounds__(512) void gemm_proj3(
    const h16* __restrict__ xh, const h16* __restrict__ Wts,
    h16* __restrict__ KQV)
{
    __shared__ h16 As[4][256 * 32];   // 16 KB per buf
    __shared__ h16 Bs[4][256 * 32];   // total 128 KB

    const int t = threadIdx.x;              // 0..511
    const int wave = t >> 6, lane = t & 63;
    const int quad = lane >> 4, l16 = lane & 15;
    const int mi = wave >> 2, ni = wave & 3;
    const int wm = mi * 128, wn = ni * 64;

    // XCD swizzle: 192 wgs, 192%8==0 -> bijective chunk remap (chunk 24)
    const int lin = (int)blockIdx.x + ((int)blockIdx.y << 2) + ((int)blockIdx.z << 4);
    const int swz = (lin & 7) * 24 + (lin >> 3);
    const int bx = swz & 3, by = (swz >> 2) & 3, zz = swz >> 4;

    const int m0 = by * 256, n0 = bx * 256;

    const int proj = zz >> 2, bz = zz & 3;
    const h16 *A, *Bt; h16* C;
    if (proj == 0)      { A = xh + bz * EW;       Bt = Wts;          C = KQV + bz * EW; }
    else if (proj == 1) { A = xh + (4 + bz) * EW; Bt = Wts + EW;     C = KQV + (4 + bz) * EW; }
    else                { A = Wts + 2 * EW;       Bt = xh + (8 + bz) * EW; C = KQV + (8 + bz) * EW; }

    f4 acc[8][4] = {};

    // one sub-tile = 256 rows x 32 k (A or B) = 1024 granules = 512 thr x 2
    auto stageA = [&](int buf, int k0) {
        #pragma unroll
        for (int j = 0; j < 2; ++j) {
            int g = j * 512 + t, row = g >> 2, cg = (g & 3) ^ ((row >> 1) & 3);
            async_copy16(&As[buf][g * 8], A + (long)(m0 + row) * E_DIM + k0 + cg * 8);
        }
    };
    auto stageB = [&](int buf, int k0) {
        #pragma unroll
        for (int j = 0; j < 2; ++j) {
            int g = j * 512 + t, row = g >> 2, cg = (g & 3) ^ ((row >> 1) & 3);
            async_copy16(&Bs[buf][g * 8], Bt + (long)(n0 + row) * E_DIM + k0 + cg * 8);
        }
    };

    // prologue: sub-tiles 0,1,2 in flight (12 loads); certify tile 0
    stageA(0, 0);  stageB(0, 0);
    stageA(1, 32); stageB(1, 32);
    stageA(2, 64); stageB(2, 64);
    asm volatile("s_waitcnt vmcnt(8)" ::: "memory");   // tile 0 landed
    __builtin_amdgcn_s_barrier();

    for (int H = 0; H < 32; ++H) {
        const h16* as = As[H & 3];
        const h16* bs = Bs[H & 3];
        const int kn = (H + 3) * 32;
        const bool st = (H + 3) < 32;

        // ---- phase A: frags for m-subhalf 0 + stage A-part of tile H+3 ----
        h8 bv[4], av[4];
        #pragma unroll
        for (int j = 0; j < 4; ++j) {
            int rb = wn + j * 16 + l16;
            bv[j] = *reinterpret_cast<const h8*>(&bs[(rb * 4 + (quad ^ ((rb >> 1) & 3))) * 8]);
        }
        #pragma unroll
        for (int i = 0; i < 4; ++i) {
            int ra = wm + i * 16 + l16;
            av[i] = *reinterpret_cast<const h8*>(&as[(ra * 4 + (quad ^ ((ra >> 1) & 3))) * 8]);
        }
        if (st) stageA((H + 3) & 3, kn);
        __builtin_amdgcn_s_barrier();
        __builtin_amdgcn_s_setprio(1);
        #pragma unroll
        for (int i = 0; i < 4; ++i)
            #pragma unroll
            for (int j = 0; j < 4; ++j)
                acc[i][j] = __builtin_amdgcn_mfma_f32_16x16x32_f16(av[i], bv[j], acc[i][j], 0, 0, 0);
        __builtin_amdgcn_s_setprio(0);
        __builtin_amdgcn_s_barrier();

        // ---- phase B: frags for m-subhalf 1 (bv reused) + stage B-part ----
        #pragma unroll
        for (int i = 0; i < 4; ++i) {
            int ra = wm + 64 + i * 16 + l16;
            av[i] = *reinterpret_cast<const h8*>(&as[(ra * 4 + (quad ^ ((ra >> 1) & 3))) * 8]);
        }
        if (st) stageB((H + 3) & 3, kn);
        // boundary: certify tile H+1 (H+2, H+3 stay in flight)
        if (H < 29)       asm volatile("s_waitcnt vmcnt(8)" ::: "memory");
        else if (H == 29) asm volatile("s_waitcnt vmcnt(4)" ::: "memory");
        else if (H == 30) asm volatile("s_waitcnt vmcnt(0)" ::: "memory");
        __builtin_amdgcn_s_barrier();
        __builtin_amdgcn_s_setprio(1);
        #pragma unroll
        for (int i = 0; i < 4; ++i)
            #pragma unroll
            for (int j = 0; j < 4; ++j)
                acc[4 + i][j] = __builtin_amdgcn_mfma_f32_16x16x32_f16(av[i], bv[j], acc[4 + i][j], 0, 0, 0);
        __builtin_amdgcn_s_setprio(0);
        __builtin_amdgcn_s_barrier();
    }

    #pragma unroll
    for (int mt = 0; mt < 8; ++mt)
        #pragma unroll
        for (int i = 0; i < 4; ++i) {
            int m = m0 + wm + mt * 16 + quad * 4 + i;
            #pragma unroll
            for (int nt = 0; nt < 4; ++nt)
                C[(long)m * W_DIM + n0 + wn + nt * 16 + l16] = (h16)acc[mt][nt][i];
        }
}

// ---------------------------------------------------------------------------
// Output GEMM, batch-fused: out = M[1024x1024] x Ao[4096x1024]^T (+bias).
// 64x128 tiles -> 512 blocks (R1-proven structure).
// ---------------------------------------------------------------------------
__global__ __launch_bounds__(256) void gemm_out(
    const h16* __restrict__ A, const h16* __restrict__ Bt,
    float* __restrict__ C, const float* __restrict__ bias)
{
    __shared__ h16 As[64 * 64];
    __shared__ h16 Bs[128 * 64];

    const int t = threadIdx.x;
    const int wave = t >> 6, lane = t & 63;
    const int quad = lane >> 4, l16 = lane & 15;
    const int m0 = blockIdx.y * 64, n0 = blockIdx.x * 128;
    const int wm = (wave >> 1) * 32, wn = (wave & 1) * 64;

    f4 acc[2][4] = {};

    for (int k0 = 0; k0 < 1024; k0 += 64) {
        __syncthreads();
        #pragma unroll
        for (int j = 0; j < 2; ++j) {
            int g = j * 256 + t, row = g >> 3, cg = (g & 7) ^ (row & 7);
            async_copy16(&As[g * 8], A + (long)(m0 + row) * E_DIM + k0 + cg * 8);
        }
        #pragma unroll
        for (int j = 0; j < 4; ++j) {
            int g = j * 256 + t, row = g >> 3, cg = (g & 7) ^ (row & 7);
            async_copy16(&Bs[g * 8], Bt + (long)(n0 + row) * E_DIM + k0 + cg * 8);
        }
        __syncthreads();

        h8 av[2][2], bv[4][2];
        #pragma unroll
        for (int c = 0; c < 2; ++c) {
            #pragma unroll
            for (int mt = 0; mt < 2; ++mt) {
                int r = wm + mt * 16 + l16;
                av[mt][c] = *reinterpret_cast<const h8*>(&As[(r * 8 + ((c * 4 + quad) ^ (l16 & 7))) * 8]);
            }
            #pragma unroll
            for (int nt = 0; nt < 4; ++nt) {
                int r = wn + nt * 16 + l16;
                bv[nt][c] = *reinterpret_cast<const h8*>(&Bs[(r * 8 + ((c * 4 + quad) ^ (l16 & 7))) * 8]);
            }
        }
        #pragma unroll
        for (int c = 0; c < 2; ++c)
            #pragma unroll
            for (int mt = 0; mt < 2; ++mt)
                #pragma unroll
                for (int nt = 0; nt < 4; ++nt)
                    acc[mt][nt] = __builtin_amdgcn_mfma_f32_16x16x32_f16(av[mt][c], bv[nt][c], acc[mt][nt], 0, 0, 0);
    }

    #pragma unroll
    for (int mt = 0; mt < 2; ++mt)
        #pragma unroll
        for (int i = 0; i < 4; ++i) {
            int m = m0 + wm + mt * 16 + quad * 4 + i;
            float bv_ = bias ? bias[m] : 0.f;
            #pragma unroll
            for (int nt = 0; nt < 4; ++nt) {
                int n = n0 + wn + nt * 16 + l16;   // n = b*1024 + w
                C[(long)(n >> 10) * EW + (long)m * W_DIM + (n & 1023)] = acc[mt][nt][i] + bv_;
            }
        }
}

// ---------------------------------------------------------------------------
// MFMA flash attention (softmax over q), 8-WAVE blocks (512 thr) — R6 version.
// ---------------------------------------------------------------------------
__global__ __launch_bounds__(512) void attn_mfma(
    const h16* __restrict__ Kt, const h16* __restrict__ Qt,
    const h16* __restrict__ V, h16* __restrict__ AoT)
{
    __shared__ h16 Qs[2][64 * 64];   // [q][d] swizzled granules (8 KB each)
    __shared__ h16 Vs[2][64 * 64];   // [d][q] swizzled granules
    __shared__ h16 Ps[8][16 * 64];   // per-wave P^T [k16][q64] swizzled granules

    const int t = threadIdx.x, wave = t >> 6, lane = t & 63;
    const int quad = lane >> 4, l16 = lane & 15;
    const int y = blockIdx.y;
    const int b = y >> 4, h = y & 15;
    const int cxor = (y & 7) ^ (((y >> 5) & 1) ? 7 : 0);
    const int ktb = (int)blockIdx.x ^ cxor;     // 0..7; id & id+256 complementary
    const int nit = 2 * ktb + 2;                // staging iterations (block-wide)
    const int kwave = ktb * 128 + wave * 16;    // wave's first k column
    const int kc = kwave + l16;                 // this lane's k column

    const h16* Ktb_ = Kt + (long)b * EW + h * 64;
    const h16* Qtb  = Qt + (long)b * EW + h * 64;
    const h16* Vb   = V  + (long)b * EW + (long)(h * 64) * W_DIM;
    h16* Pw = &Ps[wave][0];

    // K in registers: half c -> K^T[kc][c*32 + quad*8 + j]
    h8 kb0 = *reinterpret_cast<const h8*>(Ktb_ + (long)kc * E_DIM + quad * 8);
    h8 kb1 = *reinterpret_cast<const h8*>(Ktb_ + (long)kc * E_DIM + 32 + quad * 8);

    // stage tile 0 into buf 0 (512 threads x 16B = full 8 KB tile each)
    {
        int row = t >> 3, cg = (t & 7) ^ (row & 7);
        async_copy16(&Qs[0][t * 8], Qtb + (long)row * E_DIM + cg * 8);
        async_copy16(&Vs[0][t * 8], Vb + (long)row * W_DIM + cg * 8);
    }

    const float L2E = 1.442695041f;
    float mr = -1e30f, ls = 0.f;
    f4 O[4] = {};

    for (int it = 0; it < nit; ++it) {
        const int q0 = it * 64;
        __syncthreads();   // drains DMA for buf it&1; prev iter's readers done
        if (it + 1 < nit) {
            const int nb = (it + 1) & 1, q1 = q0 + 64;
            int row = t >> 3, cg = (t & 7) ^ (row & 7);
            async_copy16(&Qs[nb][t * 8], Qtb + (long)(q1 + row) * E_DIM + cg * 8);
            async_copy16(&Vs[nb][t * 8], Vb + (long)row * W_DIM + q1 + cg * 8);
        }
        if (q0 > kwave + 15) continue;   // wave fully masked on this q-tile

        const h16* qs = Qs[it & 1];
        const h16* vs = Vs[it & 1];

        // S^T[q][k]: row q = q0+nt*16+quad*4+i, col k = kc
        f4 S[4];
        __builtin_amdgcn_s_setprio(1);
        #pragma unroll
        for (int nt = 0; nt < 4; ++nt) {
            int row = nt * 16 + l16;
            h8 a0 = *reinterpret_cast<const h8*>(&qs[(row * 8 + (quad ^ (l16 & 7))) * 8]);
            h8 a1 = *reinterpret_cast<const h8*>(&qs[(row * 8 + ((4 + quad) ^ (l16 & 7))) * 8]);
            f4 s = {};
            s = __builtin_amdgcn_mfma_f32_16x16x32_f16(a0, kb0, s, 0, 0, 0);
            s = __builtin_amdgcn_mfma_f32_16x16x32_f16(a1, kb1, s, 0, 0, 0);
            S[nt] = s;
        }
        __builtin_amdgcn_s_setprio(0);

        if (it >= 2 * ktb) {   // diagonal region: mask q > k
            #pragma unroll
            for (int nt = 0; nt < 4; ++nt)
                #pragma unroll
                for (int i = 0; i < 4; ++i)
                    if (q0 + nt * 16 + quad * 4 + i > kc) S[nt][i] = -1e30f;
        }

        // tile max per column (in-lane tree + cross-quad xor16/xor32)
        float mx = -1e30f;
        #pragma unroll
        for (int nt = 0; nt < 4; ++nt) {
            float t0 = fmaxf(fmaxf(S[nt][0], S[nt][1]), fmaxf(S[nt][2], S[nt][3]));
            mx = fmaxf(mx, t0);
        }
        mx = fmaxf(mx, __shfl_xor(mx, 16));
        mx = fmaxf(mx, __shfl_xor(mx, 32));

        // defer-max: only rescale when the column max grew past THR=8
        if (__any(mx - mr > 8.f)) {
            float nm = fmaxf(mr, mx);
            float al = exp2f((mr - nm) * L2E);
            mr = nm;
            ls *= al;
            #pragma unroll
            for (int dt = 0; dt < 4; ++dt)
                #pragma unroll
                for (int i = 0; i < 4; ++i) O[dt][i] *= al;
        }

        const float mc = mr * L2E;
        float tsa = 0.f, tsb = 0.f;
        #pragma unroll
        for (int nt = 0; nt < 4; ++nt)
            #pragma unroll
            for (int i = 0; i < 4; ++i) {
                float p = exp2f(fmaf(S[nt][i], L2E, -mc));
                S[nt][i] = p;
                if (i & 1) tsb += p; else tsa += p;
            }
        float ts = tsa + tsb;
        ts += __shfl_xor(ts, 16);
        ts += __shfl_xor(ts, 32);
        ls += ts;

        // P^T -> per-wave LDS: row l16, swizzled granules
        #pragma unroll
        for (int nt = 0; nt < 4; ++nt) {
            int sg = ((nt * 2 + (quad >> 1)) ^ (l16 & 7)) * 8 + (quad & 1) * 4;
            union { h16 hh[4]; uint2 u2; } u0;
            #pragma unroll
            for (int i = 0; i < 4; ++i) u0.hh[i] = (h16)S[nt][i];
            *reinterpret_cast<uint2*>(Pw + l16 * 64 + sg) = u0.u2;
        }
        asm volatile("" ::: "memory");   // DS in-order per wave; read after write

        // OUT^T[d][k] += V[d][q] * P[q][k]
        __builtin_amdgcn_s_setprio(1);
        #pragma unroll
        for (int c = 0; c < 2; ++c) {
            int sg = ((c * 4 + quad) ^ (l16 & 7)) * 8;
            h8 pb = *reinterpret_cast<const h8*>(Pw + l16 * 64 + sg);
            #pragma unroll
            for (int dt = 0; dt < 4; ++dt) {
                int r = dt * 16 + l16;
                h8 va = *reinterpret_cast<const h8*>(&vs[(r * 8 + ((c * 4 + quad) ^ (l16 & 7))) * 8]);
                O[dt] = __builtin_amdgcn_mfma_f32_16x16x32_f16(va, pb, O[dt], 0, 0, 0);
            }
        }
        __builtin_amdgcn_s_setprio(0);
    }

    // epilogue: O cols k=l16, rows d -> transpose via Pw, store rows of AoT
    const float inv = 0.03125f / ls;
    #pragma unroll
    for (int dt = 0; dt < 4; ++dt) {
        int sg = ((dt * 2 + (quad >> 1)) ^ (l16 & 7)) * 8 + (quad & 1) * 4;
        union { h16 hh[4]; uint2 u2; } u0;
        #pragma unroll
        for (int i = 0; i < 4; ++i) u0.hh[i] = (h16)(O[dt][i] * inv);
        *reinterpret_cast<uint2*>(Pw + l16 * 64 + sg) = u0.u2;
    }
    asm volatile("" ::: "memory");
    #pragma unroll
    for (int j = 0; j < 2; ++j) {
        int sg = ((quad * 2 + j) ^ (l16 & 7)) * 8;
        uint4 vv = *reinterpret_cast<const uint4*>(Pw + l16 * 64 + sg);
        *reinterpret_cast<uint4*>(AoT + (long)b * EW + (long)(kwave + l16) * E_DIM
                                  + h * 64 + quad * 16 + j * 8) = vv;
    }
}

// ---------------------------------------------------------------------------
extern "C" void kernel_launch(void* const* d_in, const int* in_sizes, int n_in,
                              void* d_out, int out_size, void* d_ws, size_t ws_size,
                              hipStream_t stream)
{
    const float* x  = (const float*)d_in[0];  // [3][B][E][W]; x[0]->K, x[1]->Q, x[2]->V
    const float* LQ = (const float*)d_in[1];
    const float* LK = (const float*)d_in[2];
    const float* LV = (const float*)d_in[3];
    const float* Mw = (const float*)d_in[4];
    const float* bb = (const float*)d_in[5];
    float* out = (float*)d_out;
    h16* ws = (h16*)d_ws;

    h16* xh  = ws;                    // [12][W][E] transposed x
    h16* LKh = ws + 12 * EW;          // weights [LK|LQ|LV|M]
    h16* Mh  = ws + 15 * EW;
    h16* Kp  = ws + 16 * EW;          // [B][W][E] (K^T)
    h16* Qp  = ws + 20 * EW;          // [B][W][E] (Q^T)
    h16* Vp  = ws + 24 * EW;          // [B][E][W] (V)
    h16* Ao  = ws + 28 * EW;          // [B][W][E] (attn out^T) = [4096][1024]

    dim3 blk(256);
    prep<<<dim3(16, 16, 16), blk, 0, stream>>>(x, LK, LQ, LV, Mw, xh, LKh);
    gemm_proj3<<<dim3(4, 4, 12), dim3(512), 0, stream>>>(xh, LKh, Kp);
    attn_mfma<<<dim3(8, 64), dim3(512), 0, stream>>>(Kp, Qp, Vp, Ao);
    gemm_out<<<dim3(32, 16), blk, 0, stream>>>(Mh, Ao, out, bb);
}

// Round 10
// 186.068 us; speedup vs baseline: 1.0254x; 1.0139x over previous
//
#include <hip/hip_runtime.h>
#include <stdint.h>
#include <math.h>

#define E_DIM 1024
#define W_DIM 1024
#define EW 1048576L   // 1024*1024

typedef _Float16 h16;
typedef __attribute__((ext_vector_type(8))) _Float16 h8;
typedef __attribute__((ext_vector_type(4))) float f4;

__device__ __forceinline__ void async_copy16(h16* lds, const h16* g) {
    __builtin_amdgcn_global_load_lds(
        (const __attribute__((address_space(1))) void*)g,
        (__attribute__((address_space(3))) void*)lds, 16, 0, 0);
}

// ---------------------------------------------------------------------------
// prep: z<12 -> transpose-convert x [12][E][W] fp32 -> [12][W][E] fp16;
//       z>=12 -> convert weight (z-12) fp32 -> fp16 into wh[LK|LQ|LV|M].
// Output stores widened to uint4 (16 B/lane coalesced).
// ---------------------------------------------------------------------------
__global__ __launch_bounds__(256) void prep(
    const float* __restrict__ x, const float* __restrict__ LK,
    const float* __restrict__ LQ, const float* __restrict__ LV,
    const float* __restrict__ Mw, h16* __restrict__ xt, h16* __restrict__ wh)
{
    __shared__ float Ts[64][65];
    const int z = blockIdx.z;
    const int t = threadIdx.x;
    if (z < 12) {
        const float* src = x + (long)z * EW;   // [e][w]
        h16* dst = xt + (long)z * EW;          // [w][e]
        const int e0 = blockIdx.y * 64, w0 = blockIdx.x * 64;
        const int r = t >> 4, c4 = (t & 15) * 4;
        #pragma unroll
        for (int p = 0; p < 4; ++p) {
            float4 v = *reinterpret_cast<const float4*>(src + (long)(e0 + r + p * 16) * W_DIM + w0 + c4);
            Ts[c4 + 0][r + p * 16] = v.x;
            Ts[c4 + 1][r + p * 16] = v.y;
            Ts[c4 + 2][r + p * 16] = v.z;
            Ts[c4 + 3][r + p * 16] = v.w;
        }
        __syncthreads();
        const int r2 = t >> 3, c8 = (t & 7) * 8;
        #pragma unroll
        for (int p = 0; p < 2; ++p) {
            int wr = r2 + p * 32;
            union { h16 h[8]; uint4 u; } o;
            #pragma unroll
            for (int k = 0; k < 8; ++k) o.h[k] = (h16)Ts[wr][c8 + k];
            *reinterpret_cast<uint4*>(dst + (long)(w0 + wr) * E_DIM + e0 + c8) = o.u;
        }
    } else {
        const float* srcs[4] = {LK, LQ, LV, Mw};
        const float* s = srcs[z - 12];
        h16* o = wh + (long)(z - 12) * EW;
        long base = ((long)(blockIdx.y * 16 + blockIdx.x)) * 1024 + t;  // float4 idx
        #pragma unroll
        for (int k = 0; k < 4; ++k) {
            long i = base + k * 256;
            float4 v = reinterpret_cast<const float4*>(s)[i];
            union { h16 h[4]; uint2 u; } u;
            u.h[0] = (h16)v.x; u.h[1] = (h16)v.y; u.h[2] = (h16)v.z; u.h[3] = (h16)v.w;
            reinterpret_cast<uint2*>(o)[i] = u.u;
        }
    }
}

// ---------------------------------------------------------------------------
// Fused projection GEMMs (K, Q, V) — 256x256 tile, fine-phase pipeline
// (R9, measured 40.4 us; banked — do not touch).
// ---------------------------------------------------------------------------
__global__ __launch_bounds__(512) void gemm_proj3(
    const h16* __restrict__ xh, const h16* __restrict__ Wts,
    h16* __restrict__ KQV)
{
    __shared__ h16 As[4][256 * 32];   // 16 KB per buf
    __shared__ h16 Bs[4][256 * 32];   // total 128 KB

    const int t = threadIdx.x;              // 0..511
    const int wave = t >> 6, lane = t & 63;
    const int quad = lane >> 4, l16 = lane & 15;
    const int mi = wave >> 2, ni = wave & 3;
    const int wm = mi * 128, wn = ni * 64;

    // XCD swizzle: 192 wgs, 192%8==0 -> bijective chunk remap (chunk 24)
    const int lin = (int)blockIdx.x + ((int)blockIdx.y << 2) + ((int)blockIdx.z << 4);
    const int swz = (lin & 7) * 24 + (lin >> 3);
    const int bx = swz & 3, by = (swz >> 2) & 3, zz = swz >> 4;

    const int m0 = by * 256, n0 = bx * 256;

    const int proj = zz >> 2, bz = zz & 3;
    const h16 *A, *Bt; h16* C;
    if (proj == 0)      { A = xh + bz * EW;       Bt = Wts;          C = KQV + bz * EW; }
    else if (proj == 1) { A = xh + (4 + bz) * EW; Bt = Wts + EW;     C = KQV + (4 + bz) * EW; }
    else                { A = Wts + 2 * EW;       Bt = xh + (8 + bz) * EW; C = KQV + (8 + bz) * EW; }

    f4 acc[8][4] = {};

    auto stageA = [&](int buf, int k0) {
        #pragma unroll
        for (int j = 0; j < 2; ++j) {
            int g = j * 512 + t, row = g >> 2, cg = (g & 3) ^ ((row >> 1) & 3);
            async_copy16(&As[buf][g * 8], A + (long)(m0 + row) * E_DIM + k0 + cg * 8);
        }
    };
    auto stageB = [&](int buf, int k0) {
        #pragma unroll
        for (int j = 0; j < 2; ++j) {
            int g = j * 512 + t, row = g >> 2, cg = (g & 3) ^ ((row >> 1) & 3);
            async_copy16(&Bs[buf][g * 8], Bt + (long)(n0 + row) * E_DIM + k0 + cg * 8);
        }
    };

    stageA(0, 0);  stageB(0, 0);
    stageA(1, 32); stageB(1, 32);
    stageA(2, 64); stageB(2, 64);
    asm volatile("s_waitcnt vmcnt(8)" ::: "memory");   // tile 0 landed
    __builtin_amdgcn_s_barrier();

    for (int H = 0; H < 32; ++H) {
        const h16* as = As[H & 3];
        const h16* bs = Bs[H & 3];
        const int kn = (H + 3) * 32;
        const bool st = (H + 3) < 32;

        // ---- phase A: frags for m-subhalf 0 + stage A-part of tile H+3 ----
        h8 bv[4], av[4];
        #pragma unroll
        for (int j = 0; j < 4; ++j) {
            int rb = wn + j * 16 + l16;
            bv[j] = *reinterpret_cast<const h8*>(&bs[(rb * 4 + (quad ^ ((rb >> 1) & 3))) * 8]);
        }
        #pragma unroll
        for (int i = 0; i < 4; ++i) {
            int ra = wm + i * 16 + l16;
            av[i] = *reinterpret_cast<const h8*>(&as[(ra * 4 + (quad ^ ((ra >> 1) & 3))) * 8]);
        }
        if (st) stageA((H + 3) & 3, kn);
        __builtin_amdgcn_s_barrier();
        __builtin_amdgcn_s_setprio(1);
        #pragma unroll
        for (int i = 0; i < 4; ++i)
            #pragma unroll
            for (int j = 0; j < 4; ++j)
                acc[i][j] = __builtin_amdgcn_mfma_f32_16x16x32_f16(av[i], bv[j], acc[i][j], 0, 0, 0);
        __builtin_amdgcn_s_setprio(0);
        __builtin_amdgcn_s_barrier();

        // ---- phase B: frags for m-subhalf 1 (bv reused) + stage B-part ----
        #pragma unroll
        for (int i = 0; i < 4; ++i) {
            int ra = wm + 64 + i * 16 + l16;
            av[i] = *reinterpret_cast<const h8*>(&as[(ra * 4 + (quad ^ ((ra >> 1) & 3))) * 8]);
        }
        if (st) stageB((H + 3) & 3, kn);
        if (H < 29)       asm volatile("s_waitcnt vmcnt(8)" ::: "memory");
        else if (H == 29) asm volatile("s_waitcnt vmcnt(4)" ::: "memory");
        else if (H == 30) asm volatile("s_waitcnt vmcnt(0)" ::: "memory");
        __builtin_amdgcn_s_barrier();
        __builtin_amdgcn_s_setprio(1);
        #pragma unroll
        for (int i = 0; i < 4; ++i)
            #pragma unroll
            for (int j = 0; j < 4; ++j)
                acc[4 + i][j] = __builtin_amdgcn_mfma_f32_16x16x32_f16(av[i], bv[j], acc[4 + i][j], 0, 0, 0);
        __builtin_amdgcn_s_setprio(0);
        __builtin_amdgcn_s_barrier();
    }

    #pragma unroll
    for (int mt = 0; mt < 8; ++mt)
        #pragma unroll
        for (int i = 0; i < 4; ++i) {
            int m = m0 + wm + mt * 16 + quad * 4 + i;
            #pragma unroll
            for (int nt = 0; nt < 4; ++nt)
                C[(long)m * W_DIM + n0 + wn + nt * 16 + l16] = (h16)acc[mt][nt][i];
        }
}

// ---------------------------------------------------------------------------
// Output GEMM, batch-fused: out = M[1024x1024] x Ao[4096x1024]^T (+bias).
// 64x128 tiles -> 512 blocks (R1-proven structure).
// ---------------------------------------------------------------------------
__global__ __launch_bounds__(256) void gemm_out(
    const h16* __restrict__ A, const h16* __restrict__ Bt,
    float* __restrict__ C, const float* __restrict__ bias)
{
    __shared__ h16 As[64 * 64];
    __shared__ h16 Bs[128 * 64];

    const int t = threadIdx.x;
    const int wave = t >> 6, lane = t & 63;
    const int quad = lane >> 4, l16 = lane & 15;
    const int m0 = blockIdx.y * 64, n0 = blockIdx.x * 128;
    const int wm = (wave >> 1) * 32, wn = (wave & 1) * 64;

    f4 acc[2][4] = {};

    for (int k0 = 0; k0 < 1024; k0 += 64) {
        __syncthreads();
        #pragma unroll
        for (int j = 0; j < 2; ++j) {
            int g = j * 256 + t, row = g >> 3, cg = (g & 7) ^ (row & 7);
            async_copy16(&As[g * 8], A + (long)(m0 + row) * E_DIM + k0 + cg * 8);
        }
        #pragma unroll
        for (int j = 0; j < 4; ++j) {
            int g = j * 256 + t, row = g >> 3, cg = (g & 7) ^ (row & 7);
            async_copy16(&Bs[g * 8], Bt + (long)(n0 + row) * E_DIM + k0 + cg * 8);
        }
        __syncthreads();

        h8 av[2][2], bv[4][2];
        #pragma unroll
        for (int c = 0; c < 2; ++c) {
            #pragma unroll
            for (int mt = 0; mt < 2; ++mt) {
                int r = wm + mt * 16 + l16;
                av[mt][c] = *reinterpret_cast<const h8*>(&As[(r * 8 + ((c * 4 + quad) ^ (l16 & 7))) * 8]);
            }
            #pragma unroll
            for (int nt = 0; nt < 4; ++nt) {
                int r = wn + nt * 16 + l16;
                bv[nt][c] = *reinterpret_cast<const h8*>(&Bs[(r * 8 + ((c * 4 + quad) ^ (l16 & 7))) * 8]);
            }
        }
        #pragma unroll
        for (int c = 0; c < 2; ++c)
            #pragma unroll
            for (int mt = 0; mt < 2; ++mt)
                #pragma unroll
                for (int nt = 0; nt < 4; ++nt)
                    acc[mt][nt] = __builtin_amdgcn_mfma_f32_16x16x32_f16(av[mt][c], bv[nt][c], acc[mt][nt], 0, 0, 0);
    }

    #pragma unroll
    for (int mt = 0; mt < 2; ++mt)
        #pragma unroll
        for (int i = 0; i < 4; ++i) {
            int m = m0 + wm + mt * 16 + quad * 4 + i;
            float bv_ = bias ? bias[m] : 0.f;
            #pragma unroll
            for (int nt = 0; nt < 4; ++nt) {
                int n = n0 + wn + nt * 16 + l16;   // n = b*1024 + w
                C[(long)(n >> 10) * EW + (long)m * W_DIM + (n & 1023)] = acc[mt][nt][i] + bv_;
            }
        }
}

// ---------------------------------------------------------------------------
// MFMA flash attention (softmax over q), 8-wave blocks, QBLK=128:
//  - each iteration stages TWO 64-q subtiles (side-by-side 64x64 tiles,
//    same proven swizzle) behind ONE barrier -> barrier count halved
//    (critical ktb=7 block: 8 barriers instead of 16)
//  - per iteration: process sub=0,1 sequentially with the R6 body
//  - LDS 80 KB -> still 2 blocks/CU (grid 512 = 2/CU, residency unchanged)
// ---------------------------------------------------------------------------
__global__ __launch_bounds__(512) void attn_mfma(
    const h16* __restrict__ Kt, const h16* __restrict__ Qt,
    const h16* __restrict__ V, h16* __restrict__ AoT)
{
    __shared__ h16 Qs[2][2][64 * 64];   // [buf][sub][q][d] swizzled granules
    __shared__ h16 Vs[2][2][64 * 64];   // [buf][sub][d][q] swizzled granules
    __shared__ h16 Ps[8][16 * 64];      // per-wave P^T [k16][q64]

    const int t = threadIdx.x, wave = t >> 6, lane = t & 63;
    const int quad = lane >> 4, l16 = lane & 15;
    const int y = blockIdx.y;
    const int b = y >> 4, h = y & 15;
    const int cxor = (y & 7) ^ (((y >> 5) & 1) ? 7 : 0);
    const int ktb = (int)blockIdx.x ^ cxor;     // 0..7; id & id+256 complementary
    const int nit = ktb + 1;                    // 128-q iterations (block-wide)
    const int kwave = ktb * 128 + wave * 16;    // wave's first k column
    const int kc = kwave + l16;                 // this lane's k column

    const h16* Ktb_ = Kt + (long)b * EW + h * 64;
    const h16* Qtb  = Qt + (long)b * EW + h * 64;
    const h16* Vb   = V  + (long)b * EW + (long)(h * 64) * W_DIM;
    h16* Pw = &Ps[wave][0];

    // K in registers: half c -> K^T[kc][c*32 + quad*8 + j]
    h8 kb0 = *reinterpret_cast<const h8*>(Ktb_ + (long)kc * E_DIM + quad * 8);
    h8 kb1 = *reinterpret_cast<const h8*>(Ktb_ + (long)kc * E_DIM + 32 + quad * 8);

    const int srow = t >> 3, scg = (t & 7) ^ (srow & 7);
    // stage tile 0 (both 64-q subtiles) into buf 0
    #pragma unroll
    for (int hs = 0; hs < 2; ++hs) {
        async_copy16(&Qs[0][hs][t * 8], Qtb + (long)(hs * 64 + srow) * E_DIM + scg * 8);
        async_copy16(&Vs[0][hs][t * 8], Vb + (long)srow * W_DIM + hs * 64 + scg * 8);
    }

    const float L2E = 1.442695041f;
    float mr = -1e30f, ls = 0.f;
    f4 O[4] = {};

    for (int it = 0; it < nit; ++it) {
        const int q0 = it * 128;
        __syncthreads();   // drains DMA for buf it&1 (issued a full iter ago)
        if (it + 1 < nit) {
            const int nb = (it + 1) & 1, q1 = q0 + 128;
            #pragma unroll
            for (int hs = 0; hs < 2; ++hs) {
                async_copy16(&Qs[nb][hs][t * 8], Qtb + (long)(q1 + hs * 64 + srow) * E_DIM + scg * 8);
                async_copy16(&Vs[nb][hs][t * 8], Vb + (long)srow * W_DIM + q1 + hs * 64 + scg * 8);
            }
        }

        for (int sub = 0; sub < 2; ++sub) {
            const int q0s = q0 + sub * 64;
            if (q0s > kwave + 15) continue;   // wave fully masked on this subtile

            const h16* qs = &Qs[it & 1][sub][0];
            const h16* vs = &Vs[it & 1][sub][0];

            // S^T[q][k]: row q = q0s+nt*16+quad*4+i, col k = kc
            f4 S[4];
            __builtin_amdgcn_s_setprio(1);
            #pragma unroll
            for (int nt = 0; nt < 4; ++nt) {
                int row = nt * 16 + l16;
                h8 a0 = *reinterpret_cast<const h8*>(&qs[(row * 8 + (quad ^ (l16 & 7))) * 8]);
                h8 a1 = *reinterpret_cast<const h8*>(&qs[(row * 8 + ((4 + quad) ^ (l16 & 7))) * 8]);
                f4 s = {};
                s = __builtin_amdgcn_mfma_f32_16x16x32_f16(a0, kb0, s, 0, 0, 0);
                s = __builtin_amdgcn_mfma_f32_16x16x32_f16(a1, kb1, s, 0, 0, 0);
                S[nt] = s;
            }
            __builtin_amdgcn_s_setprio(0);

            if (2 * it + sub >= 2 * ktb) {   // diagonal region: mask q > k
                #pragma unroll
                for (int nt = 0; nt < 4; ++nt)
                    #pragma unroll
                    for (int i = 0; i < 4; ++i)
                        if (q0s + nt * 16 + quad * 4 + i > kc) S[nt][i] = -1e30f;
            }

            // subtile max per column (in-lane tree + cross-quad xor16/xor32)
            float mx = -1e30f;
            #pragma unroll
            for (int nt = 0; nt < 4; ++nt) {
                float t0 = fmaxf(fmaxf(S[nt][0], S[nt][1]), fmaxf(S[nt][2], S[nt][3]));
                mx = fmaxf(mx, t0);
            }
            mx = fmaxf(mx, __shfl_xor(mx, 16));
            mx = fmaxf(mx, __shfl_xor(mx, 32));

            // defer-max: only rescale when the column max grew past THR=8
            if (__any(mx - mr > 8.f)) {
                float nm = fmaxf(mr, mx);
                float al = exp2f((mr - nm) * L2E);
                mr = nm;
                ls *= al;
                #pragma unroll
                for (int dt = 0; dt < 4; ++dt)
                    #pragma unroll
                    for (int i = 0; i < 4; ++i) O[dt][i] *= al;
            }

            const float mc = mr * L2E;
            float tsa = 0.f, tsb = 0.f;
            #pragma unroll
            for (int nt = 0; nt < 4; ++nt)
                #pragma unroll
                for (int i = 0; i < 4; ++i) {
                    float p = exp2f(fmaf(S[nt][i], L2E, -mc));
                    S[nt][i] = p;
                    if (i & 1) tsb += p; else tsa += p;
                }
            float ts = tsa + tsb;
            ts += __shfl_xor(ts, 16);
            ts += __shfl_xor(ts, 32);
            ls += ts;

            // P^T -> per-wave LDS: row l16, swizzled granules
            #pragma unroll
            for (int nt = 0; nt < 4; ++nt) {
                int sg = ((nt * 2 + (quad >> 1)) ^ (l16 & 7)) * 8 + (quad & 1) * 4;
                union { h16 hh[4]; uint2 u2; } u0;
                #pragma unroll
                for (int i = 0; i < 4; ++i) u0.hh[i] = (h16)S[nt][i];
                *reinterpret_cast<uint2*>(Pw + l16 * 64 + sg) = u0.u2;
            }
            asm volatile("" ::: "memory");   // DS in-order per wave

            // OUT^T[d][k] += V[d][q] * P[q][k]
            __builtin_amdgcn_s_setprio(1);
            #pragma unroll
            for (int c = 0; c < 2; ++c) {
                int sg = ((c * 4 + quad) ^ (l16 & 7)) * 8;
                h8 pb = *reinterpret_cast<const h8*>(Pw + l16 * 64 + sg);
                #pragma unroll
                for (int dt = 0; dt < 4; ++dt) {
                    int r = dt * 16 + l16;
                    h8 va = *reinterpret_cast<const h8*>(&vs[(r * 8 + ((c * 4 + quad) ^ (l16 & 7))) * 8]);
                    O[dt] = __builtin_amdgcn_mfma_f32_16x16x32_f16(va, pb, O[dt], 0, 0, 0);
                }
            }
            __builtin_amdgcn_s_setprio(0);
            asm volatile("" ::: "memory");   // P reads done before next sub's writes
        }
    }

    // epilogue: O cols k=l16, rows d -> transpose via Pw, store rows of AoT
    const float inv = 0.03125f / ls;
    #pragma unroll
    for (int dt = 0; dt < 4; ++dt) {
        int sg = ((dt * 2 + (quad >> 1)) ^ (l16 & 7)) * 8 + (quad & 1) * 4;
        union { h16 hh[4]; uint2 u2; } u0;
        #pragma unroll
        for (int i = 0; i < 4; ++i) u0.hh[i] = (h16)(O[dt][i] * inv);
        *reinterpret_cast<uint2*>(Pw + l16 * 64 + sg) = u0.u2;
    }
    asm volatile("" ::: "memory");
    #pragma unroll
    for (int j = 0; j < 2; ++j) {
        int sg = ((quad * 2 + j) ^ (l16 & 7)) * 8;
        uint4 vv = *reinterpret_cast<const uint4*>(Pw + l16 * 64 + sg);
        *reinterpret_cast<uint4*>(AoT + (long)b * EW + (long)(kwave + l16) * E_DIM
                                  + h * 64 + quad * 16 + j * 8) = vv;
    }
}

// ---------------------------------------------------------------------------
extern "C" void kernel_launch(void* const* d_in, const int* in_sizes, int n_in,
                              void* d_out, int out_size, void* d_ws, size_t ws_size,
                              hipStream_t stream)
{
    const float* x  = (const float*)d_in[0];  // [3][B][E][W]; x[0]->K, x[1]->Q, x[2]->V
    const float* LQ = (const float*)d_in[1];
    const float* LK = (const float*)d_in[2];
    const float* LV = (const float*)d_in[3];
    const float* Mw = (const float*)d_in[4];
    const float* bb = (const float*)d_in[5];
    float* out = (float*)d_out;
    h16* ws = (h16*)d_ws;

    h16* xh  = ws;                    // [12][W][E] transposed x
    h16* LKh = ws + 12 * EW;          // weights [LK|LQ|LV|M]
    h16* Mh  = ws + 15 * EW;
    h16* Kp  = ws + 16 * EW;          // [B][W][E] (K^T)
    h16* Qp  = ws + 20 * EW;          // [B][W][E] (Q^T)
    h16* Vp  = ws + 24 * EW;          // [B][E][W] (V)
    h16* Ao  = ws + 28 * EW;          // [B][W][E] (attn out^T) = [4096][1024]

    dim3 blk(256);
    prep<<<dim3(16, 16, 16), blk, 0, stream>>>(x, LK, LQ, LV, Mw, xh, LKh);
    gemm_proj3<<<dim3(4, 4, 12), dim3(512), 0, stream>>>(xh, LKh, Kp);
    attn_mfma<<<dim3(8, 64), dim3(512), 0, stream>>>(Kp, Qp, Vp, Ao);
    gemm_out<<<dim3(32, 16), blk, 0, stream>>>(Mh, Ao, out, bb);
}